// Round 9
// baseline (75.550 us; speedup 1.0000x reference)
//
#include <hip/hip_runtime.h>
#include <hip/hip_bf16.h>

#define B_ 4
#define Q_ 256
#define K_ 1024
#define D_ 256
#define LOG2E 1.44269504f

__device__ __forceinline__ float fexp2(float x) {
    float r; asm("v_exp_f32 %0, %1" : "=v"(r) : "v"(x)); return r;
}
__device__ __forceinline__ float frcp(float x) {
    float r; asm("v_rcp_f32 %0, %1" : "=v"(r) : "v"(x)); return r;
}

// Fused: blocks (x<80, y) do the two projections (output = exp2(c2 * A@W));
// blocks (80, y) do per-batch mask compaction.
__global__ __launch_bounds__(256) void prep_kernel(const float* __restrict__ q,
                                                   const float* __restrict__ k,
                                                   const float* __restrict__ Wq,
                                                   const float* __restrict__ Wk,
                                                   const int* __restrict__ mask,
                                                   float* __restrict__ qpE,
                                                   float* __restrict__ kpE,
                                                   ushort* __restrict__ kidx,
                                                   int* __restrict__ nvalid,
                                                   float scale) {
    const int t = threadIdx.x;
    if (blockIdx.x >= 80) {
        if (t >= 64) return;
        const int b = blockIdx.y, lane = t;
        const int* m = mask + b * K_;
        const int base = lane * 16;
        int cnt = 0;
#pragma unroll
        for (int i = 0; i < 16; ++i) cnt += (m[base + i] != 0);
        int inc = cnt;
#pragma unroll
        for (int d = 1; d < 64; d <<= 1) {
            int tt = __shfl_up(inc, d);
            if (lane >= d) inc += tt;
        }
        const int total = __shfl(inc, 63);
        int pos = inc - cnt;
        ushort* kb = kidx + b * K_;
        for (int i = 0; i < 16; ++i) {
            int kk = base + i;
            if (m[kk] != 0) kb[pos++] = (ushort)kk;
        }
        for (int j = total + lane; j < K_; j += 64) kb[j] = 0;
        if (lane == 0) nvalid[b] = total;
        return;
    }
    const float* A; const float* W; float* outp; int m0;
    if (blockIdx.x < 16) { A = q; W = Wq; outp = qpE; m0 = blockIdx.x * 64; }
    else                 { A = k; W = Wk; outp = kpE; m0 = (blockIdx.x - 16) * 64; }
    __shared__ float As[16][65];
    __shared__ float Ws[16][64];
    const int tx = t & 15, ty = t >> 4;
    const int n0 = blockIdx.y * 64;
    const int ar = t >> 2, ac = (t & 3) * 4;
    const int wr = t >> 4, wc = (t & 15) * 4;
    float c[4][4] = {};
    for (int kb = 0; kb < 256; kb += 16) {
        __syncthreads();
        float4 av = *(const float4*)(A + (size_t)(m0 + ar) * 256 + kb + ac);
        As[ac + 0][ar] = av.x; As[ac + 1][ar] = av.y;
        As[ac + 2][ar] = av.z; As[ac + 3][ar] = av.w;
        float4 wvv = *(const float4*)(W + (size_t)(kb + wr) * 256 + n0 + wc);
        wvv.x *= scale; wvv.y *= scale; wvv.z *= scale; wvv.w *= scale;
        *(float4*)(&Ws[wr][wc]) = wvv;
        __syncthreads();
#pragma unroll
        for (int kk = 0; kk < 16; ++kk) {
            float4 bv = *(const float4*)(&Ws[kk][tx * 4]);
#pragma unroll
            for (int i = 0; i < 4; ++i) {
                float a = As[kk][ty * 4 + i];
                c[i][0] = fmaf(a, bv.x, c[i][0]);
                c[i][1] = fmaf(a, bv.y, c[i][1]);
                c[i][2] = fmaf(a, bv.z, c[i][2]);
                c[i][3] = fmaf(a, bv.w, c[i][3]);
            }
        }
    }
#pragma unroll
    for (int i = 0; i < 4; ++i) {
        float4 o = make_float4(fexp2(c[i][0]), fexp2(c[i][1]),
                               fexp2(c[i][2]), fexp2(c[i][3]));
        *(float4*)(outp + (size_t)(m0 + ty * 4 + i) * 256 + n0 + tx * 4) = o;
    }
}

// Grid = 512 = B * 128 qpairs, 512 threads, ~29 KB LDS -> 4 blocks/CU (100% occ).
// LANE OWNS K: each thread computes the full 256-e sigmoid dot for its own
// compacted k (q0 and q1 together). No cross-lane/cross-wave reduction at all;
// only 3 block barriers in the whole kernel. Block-uniform qp_A rows and wv
// live in LDS and are read as broadcast float4s; kp rows stream from L2/L1.
// sigmoid(2(qp+kp)) = 1/(A*B+1) with A=exp2(c*qp), B=exp2(c*kp) precomputed.
__global__ __launch_bounds__(512, 4) void attn_kernel(const float* __restrict__ qpE,
                                                      const float* __restrict__ kpE,
                                                      const float* __restrict__ v,
                                                      const ushort* __restrict__ kidx_g,
                                                      const int* __restrict__ nvalid_g,
                                                      const float* __restrict__ wv,
                                                      float* __restrict__ out) {
    __shared__ float  s_qpA[2][256];      //  2 KB : A = exp2(c*qp) rows (block-uniform)
    __shared__ float  s_wv[256];          //  1 KB
    __shared__ ushort s_kidx[1024];       //  2 KB : compacted k indices
    __shared__ float  s_sc[2][1024];      //  8 KB : scores then unnormalized probs
    __shared__ float4 s_pv[16][64];       // 16 KB : PV partials (8 kq x 2 q)
    __shared__ float  s_inv[2];

    const int tid = threadIdx.x;

    int bid = blockIdx.x;
    bid = (bid & 7) * 64 + (bid >> 3);    // bijective XCD swizzle (512 % 8 == 0)
    const int b  = bid >> 7;
    const int qi = bid & 127;
    const int q0 = qi * 2;

    const int nv = nvalid_g[b];

    // stage block-uniform operands + indices
    if (tid < 64)        ((float4*)s_qpA[0])[tid]      = ((const float4*)(qpE + ((size_t)(b * Q_ + q0)     << 8)))[tid];
    else if (tid < 128)  ((float4*)s_qpA[1])[tid - 64] = ((const float4*)(qpE + ((size_t)(b * Q_ + q0 + 1) << 8)))[tid - 64];
    else if (tid < 192)  ((float4*)s_wv)[tid - 128]    = ((const float4*)wv)[tid - 128];
    s_kidx[tid]       = (tid < nv)       ? kidx_g[b * K_ + tid]       : (ushort)0;
    s_kidx[tid + 512] = (tid + 512 < nv) ? kidx_g[b * K_ + tid + 512] : (ushort)0;
    __syncthreads();

    // ---- scores: lane owns k, full in-lane 256-e dot ----
    for (int slot = tid; slot < nv; slot += 512) {
        const int kk = s_kidx[slot];
        const float4* kr = (const float4*)(kpE + (((size_t)(b * K_ + kk)) << 8));
        const float4* A0p = (const float4*)s_qpA[0];
        const float4* A1p = (const float4*)s_qpA[1];
        const float4* Wp  = (const float4*)s_wv;
        float a0 = 0.f, a1 = 0.f;
#pragma unroll 4
        for (int e4 = 0; e4 < 64; ++e4) {
            float4 Bv = kr[e4];
            float4 A0 = A0p[e4];
            float4 A1 = A1p[e4];
            float4 W4 = Wp[e4];
            a0 = fmaf(W4.x, frcp(fmaf(A0.x, Bv.x, 1.f)), a0);
            a1 = fmaf(W4.x, frcp(fmaf(A1.x, Bv.x, 1.f)), a1);
            a0 = fmaf(W4.y, frcp(fmaf(A0.y, Bv.y, 1.f)), a0);
            a1 = fmaf(W4.y, frcp(fmaf(A1.y, Bv.y, 1.f)), a1);
            a0 = fmaf(W4.z, frcp(fmaf(A0.z, Bv.z, 1.f)), a0);
            a1 = fmaf(W4.z, frcp(fmaf(A1.z, Bv.z, 1.f)), a1);
            a0 = fmaf(W4.w, frcp(fmaf(A0.w, Bv.w, 1.f)), a0);
            a1 = fmaf(W4.w, frcp(fmaf(A1.w, Bv.w, 1.f)), a1);
        }
        s_sc[0][slot] = -2.f * a0;
        s_sc[1][slot] = -2.f * a1;
    }
    __syncthreads();

    // ---- softmax stats: wave qq < 2 handles q = qq ----
    const int lane = tid & 63;
    const int wave = tid >> 6;
    if (wave < 2) {
        const int qq = wave;
        float mx = -3.0e38f;
        for (int j = lane; j < nv; j += 64) mx = fmaxf(mx, s_sc[qq][j]);
#pragma unroll
        for (int off = 32; off > 0; off >>= 1) mx = fmaxf(mx, __shfl_xor(mx, off));
        float sum = 0.f;
        for (int j = lane; j < nv; j += 64) {
            float e = fexp2((s_sc[qq][j] - mx) * LOG2E);
            s_sc[qq][j] = e;
            sum += e;
        }
#pragma unroll
        for (int off = 32; off > 0; off >>= 1) sum += __shfl_xor(sum, off);
        if (lane == 0) s_inv[qq] = frcp(sum);
    }
    __syncthreads();

    // ---- PV: thread -> (d-float4 = tid&63, k stride-8 chunk = tid>>6) ----
    {
        const int dl = tid & 63;
        const int kq = tid >> 6;
        float4 o0 = {0, 0, 0, 0}, o1 = {0, 0, 0, 0};
        const float4* v4 = (const float4*)(v + ((size_t)b * K_ << 8));
        for (int k = kq; k < nv; k += 8) {
            int vr = s_kidx[k];                       // wave-uniform -> coalesced v row
            float4 vv = v4[((size_t)vr << 6) + dl];
            float p0 = s_sc[0][k], p1 = s_sc[1][k];
            o0.x = fmaf(p0, vv.x, o0.x); o0.y = fmaf(p0, vv.y, o0.y);
            o0.z = fmaf(p0, vv.z, o0.z); o0.w = fmaf(p0, vv.w, o0.w);
            o1.x = fmaf(p1, vv.x, o1.x); o1.y = fmaf(p1, vv.y, o1.y);
            o1.z = fmaf(p1, vv.z, o1.z); o1.w = fmaf(p1, vv.w, o1.w);
        }
        s_pv[kq * 2 + 0][dl] = o0;
        s_pv[kq * 2 + 1][dl] = o1;
        __syncthreads();
        if (tid < 128) {
            const int qq = tid >> 6, c = tid & 63;
            float4 s = {0, 0, 0, 0};
#pragma unroll
            for (int g = 0; g < 8; ++g) {
                float4 x = s_pv[g * 2 + qq][c];
                s.x += x.x; s.y += x.y; s.z += x.z; s.w += x.w;
            }
            const float inv = s_inv[qq];
            s.x *= inv; s.y *= inv; s.z *= inv; s.w *= inv;
            ((float4*)out)[((size_t)(b * Q_ + q0 + qq) << 6) + c] = s;
        }
    }
}

extern "C" void kernel_launch(void* const* d_in, const int* in_sizes, int n_in,
                              void* d_out, int out_size, void* d_ws, size_t ws_size,
                              hipStream_t stream) {
    const float* q    = (const float*)d_in[0];
    const float* k    = (const float*)d_in[1];
    const float* v    = (const float*)d_in[2];
    const int*   mask = (const int*)d_in[3];
    const float* Wq   = (const float*)d_in[4];
    const float* Wk   = (const float*)d_in[5];
    const float* wv   = (const float*)d_in[6];
    float* out = (float*)d_out;

    float* qpE    = (float*)d_ws;                          // 1 MB  (exp2 of c2*qp)
    float* kpE    = qpE + (size_t)B_ * Q_ * D_;            // 4 MB  (exp2 of c2*kp)
    ushort* kidx  = (ushort*)(kpE + (size_t)B_ * K_ * D_); // 8 KB
    int* nvalid   = (int*)(kidx + (size_t)B_ * K_);        // 16 B

    const float c2 = 2.885390082f;  // 2*log2(e)

    prep_kernel<<<dim3(81, 4), 256, 0, stream>>>(q, k, Wq, Wk, mask, qpE, kpE, kidx, nvalid, c2);
    attn_kernel<<<dim3(512), 512, 0, stream>>>(qpE, kpE, v, kidx, nvalid, wv, out);
}

// Round 10
// 67.355 us; speedup vs baseline: 1.1217x; 1.1217x over previous
//
#include <hip/hip_runtime.h>
#include <hip/hip_bf16.h>

#define B_ 4
#define Q_ 256
#define K_ 1024
#define D_ 256
#define NVPAD 1024
#define LOG2E 1.44269504f

__device__ __forceinline__ float fexp2(float x) {
    float r; asm("v_exp_f32 %0, %1" : "=v"(r) : "v"(x)); return r;
}
__device__ __forceinline__ float frcp(float x) {
    float r; asm("v_rcp_f32 %0, %1" : "=v"(r) : "v"(x)); return r;
}

// Grid = B, 64 threads. kidx[slot]=k, slot_of[k]=slot or -1, nvalid.
__global__ void compact_kernel(const int* __restrict__ mask,
                               ushort* __restrict__ kidx,
                               short* __restrict__ slot_of,
                               int* __restrict__ nvalid) {
    const int b = blockIdx.x, lane = threadIdx.x;
    const int* m = mask + b * K_;
    const int base = lane * 16;
    int cnt = 0;
#pragma unroll
    for (int i = 0; i < 16; ++i) cnt += (m[base + i] != 0);
    int inc = cnt;
#pragma unroll
    for (int d = 1; d < 64; d <<= 1) {
        int tt = __shfl_up(inc, d);
        if (lane >= d) inc += tt;
    }
    const int total = __shfl(inc, 63);
    int pos = inc - cnt;
    ushort* kb = kidx + b * K_;
    short* so  = slot_of + b * K_;
    for (int i = 0; i < 16; ++i) {
        int kk = base + i;
        if (m[kk] != 0) { kb[pos] = (ushort)kk; so[kk] = (short)pos; ++pos; }
        else so[kk] = -1;
    }
    for (int j = total + lane; j < K_; j += 64) kb[j] = 0;
    if (lane == 0) nvalid[b] = total;
}

// Grid (80,4), 256 thr. x<16: qpE[row][e] = exp2(c*q@Wq) row-major.
// x>=16: kpC[b][e][slot] = exp2(c*k@Wk)  (transposed + compacted scatter write).
__global__ __launch_bounds__(256) void proj_kernel(const float* __restrict__ q,
                                                   const float* __restrict__ k,
                                                   const float* __restrict__ Wq,
                                                   const float* __restrict__ Wk,
                                                   const short* __restrict__ slot_of,
                                                   float* __restrict__ qpE,
                                                   float* __restrict__ kpC,
                                                   float scale) {
    const int t = threadIdx.x;
    const bool isQ = blockIdx.x < 16;
    const float* A; const float* W; int m0;
    if (isQ) { A = q; W = Wq; m0 = blockIdx.x * 64; }
    else     { A = k; W = Wk; m0 = (blockIdx.x - 16) * 64; }

    __shared__ float As[16][65];
    __shared__ float Ws[16][64];
    __shared__ short s_slot[64];
    if (!isQ && t < 64) s_slot[t] = slot_of[m0 + t];   // m0 is global B*K row

    const int tx = t & 15, ty = t >> 4;
    const int n0 = blockIdx.y * 64;
    const int ar = t >> 2, ac = (t & 3) * 4;
    const int wr = t >> 4, wc = (t & 15) * 4;
    float c[4][4] = {};
    for (int kb = 0; kb < 256; kb += 16) {
        __syncthreads();
        float4 av = *(const float4*)(A + (size_t)(m0 + ar) * 256 + kb + ac);
        As[ac + 0][ar] = av.x; As[ac + 1][ar] = av.y;
        As[ac + 2][ar] = av.z; As[ac + 3][ar] = av.w;
        float4 wvv = *(const float4*)(W + (size_t)(kb + wr) * 256 + n0 + wc);
        wvv.x *= scale; wvv.y *= scale; wvv.z *= scale; wvv.w *= scale;
        *(float4*)(&Ws[wr][wc]) = wvv;
        __syncthreads();
#pragma unroll
        for (int kk = 0; kk < 16; ++kk) {
            float4 bv = *(const float4*)(&Ws[kk][tx * 4]);
#pragma unroll
            for (int i = 0; i < 4; ++i) {
                float a = As[kk][ty * 4 + i];
                c[i][0] = fmaf(a, bv.x, c[i][0]);
                c[i][1] = fmaf(a, bv.y, c[i][1]);
                c[i][2] = fmaf(a, bv.z, c[i][2]);
                c[i][3] = fmaf(a, bv.w, c[i][3]);
            }
        }
    }
    if (isQ) {
#pragma unroll
        for (int i = 0; i < 4; ++i) {
            float4 o = make_float4(fexp2(c[i][0]), fexp2(c[i][1]),
                                   fexp2(c[i][2]), fexp2(c[i][3]));
            *(float4*)(qpE + (size_t)(m0 + ty * 4 + i) * 256 + n0 + tx * 4) = o;
        }
    } else {
        const int b = m0 >> 10;                        // batch of this k-tile
        float* kpCb = kpC + (size_t)b * 256 * NVPAD;
#pragma unroll
        for (int i = 0; i < 4; ++i) {
            const int sl = s_slot[ty * 4 + i];
            if (sl >= 0) {
#pragma unroll
                for (int j = 0; j < 4; ++j)
                    kpCb[(size_t)(n0 + tx * 4 + j) * NVPAD + sl] = fexp2(c[i][j]);
            }
        }
    }
}

// Grid = 512 = B * 128 qpairs, 512 threads, ~29 KB LDS.
// LANE OWNS SLOT (compacted k): full in-lane 256-e sigmoid dot, but now the
// kp operand is kpC[b][e][slot] -> for fixed e, lanes read consecutive slots
// = one 256B coalesced segment per wave. A-rows (qp) and wv broadcast from LDS.
// No cross-lane reduction; 4 block barriers total.
__global__ __launch_bounds__(512, 2) void attn_kernel(const float* __restrict__ qpE,
                                                      const float* __restrict__ kpC,
                                                      const float* __restrict__ v,
                                                      const ushort* __restrict__ kidx_g,
                                                      const int* __restrict__ nvalid_g,
                                                      const float* __restrict__ wv,
                                                      float* __restrict__ out) {
    __shared__ float  s_qpA[2][256];      //  2 KB : A = exp2(c*qp) (block-uniform)
    __shared__ float  s_wv[256];          //  1 KB
    __shared__ ushort s_kidx[1024];       //  2 KB : compacted k indices (for PV)
    __shared__ float  s_sc[2][1024];      //  8 KB : scores then unnormalized probs
    __shared__ float4 s_pv[16][64];       // 16 KB : PV partials
    __shared__ float  s_inv[2];

    const int tid = threadIdx.x;

    int bid = blockIdx.x;
    bid = (bid & 7) * 64 + (bid >> 3);    // XCD swizzle: each XCD -> one batch's kpC
    const int b  = bid >> 7;
    const int qi = bid & 127;
    const int q0 = qi * 2;

    const int nv = nvalid_g[b];

    if (tid < 64)        ((float4*)s_qpA[0])[tid]      = ((const float4*)(qpE + ((size_t)(b * Q_ + q0)     << 8)))[tid];
    else if (tid < 128)  ((float4*)s_qpA[1])[tid - 64] = ((const float4*)(qpE + ((size_t)(b * Q_ + q0 + 1) << 8)))[tid - 64];
    else if (tid < 192)  ((float4*)s_wv)[tid - 128]    = ((const float4*)wv)[tid - 128];
    s_kidx[tid]       = (tid < nv)       ? kidx_g[b * K_ + tid]       : (ushort)0;
    s_kidx[tid + 512] = (tid + 512 < nv) ? kidx_g[b * K_ + tid + 512] : (ushort)0;
    __syncthreads();

    // ---- scores: lane owns slot; coalesced column reads of kpC ----
    const float* kpCb = kpC + (size_t)b * 256 * NVPAD;
    const float4* A0p = (const float4*)s_qpA[0];
    const float4* A1p = (const float4*)s_qpA[1];
    const float4* Wp  = (const float4*)s_wv;
    if (tid < nv) {
        float a0 = 0.f, a1 = 0.f;
        const float* col = kpCb + tid;
#pragma unroll 8
        for (int eg = 0; eg < 64; ++eg) {
            float4 A0 = A0p[eg], A1 = A1p[eg], W4 = Wp[eg];
            float Bx = col[(eg * 4 + 0) * NVPAD];
            float By = col[(eg * 4 + 1) * NVPAD];
            float Bz = col[(eg * 4 + 2) * NVPAD];
            float Bw = col[(eg * 4 + 3) * NVPAD];
            a0 = fmaf(W4.x, frcp(fmaf(A0.x, Bx, 1.f)), a0);
            a1 = fmaf(W4.x, frcp(fmaf(A1.x, Bx, 1.f)), a1);
            a0 = fmaf(W4.y, frcp(fmaf(A0.y, By, 1.f)), a0);
            a1 = fmaf(W4.y, frcp(fmaf(A1.y, By, 1.f)), a1);
            a0 = fmaf(W4.z, frcp(fmaf(A0.z, Bz, 1.f)), a0);
            a1 = fmaf(W4.z, frcp(fmaf(A1.z, Bz, 1.f)), a1);
            a0 = fmaf(W4.w, frcp(fmaf(A0.w, Bw, 1.f)), a0);
            a1 = fmaf(W4.w, frcp(fmaf(A1.w, Bw, 1.f)), a1);
        }
        s_sc[0][tid] = -2.f * a0;
        s_sc[1][tid] = -2.f * a1;
    }
    if (tid + 512 < nv) {
        float a0 = 0.f, a1 = 0.f;
        const float* col = kpCb + tid + 512;
#pragma unroll 8
        for (int eg = 0; eg < 64; ++eg) {
            float4 A0 = A0p[eg], A1 = A1p[eg], W4 = Wp[eg];
            float Bx = col[(eg * 4 + 0) * NVPAD];
            float By = col[(eg * 4 + 1) * NVPAD];
            float Bz = col[(eg * 4 + 2) * NVPAD];
            float Bw = col[(eg * 4 + 3) * NVPAD];
            a0 = fmaf(W4.x, frcp(fmaf(A0.x, Bx, 1.f)), a0);
            a1 = fmaf(W4.x, frcp(fmaf(A1.x, Bx, 1.f)), a1);
            a0 = fmaf(W4.y, frcp(fmaf(A0.y, By, 1.f)), a0);
            a1 = fmaf(W4.y, frcp(fmaf(A1.y, By, 1.f)), a1);
            a0 = fmaf(W4.z, frcp(fmaf(A0.z, Bz, 1.f)), a0);
            a1 = fmaf(W4.z, frcp(fmaf(A1.z, Bz, 1.f)), a1);
            a0 = fmaf(W4.w, frcp(fmaf(A0.w, Bw, 1.f)), a0);
            a1 = fmaf(W4.w, frcp(fmaf(A1.w, Bw, 1.f)), a1);
        }
        s_sc[0][tid + 512] = -2.f * a0;
        s_sc[1][tid + 512] = -2.f * a1;
    }
    __syncthreads();

    // ---- softmax stats: wave qq < 2 handles q = qq ----
    const int lane = tid & 63;
    const int wave = tid >> 6;
    if (wave < 2) {
        const int qq = wave;
        float mx = -3.0e38f;
        for (int j = lane; j < nv; j += 64) mx = fmaxf(mx, s_sc[qq][j]);
#pragma unroll
        for (int off = 32; off > 0; off >>= 1) mx = fmaxf(mx, __shfl_xor(mx, off));
        float sum = 0.f;
        for (int j = lane; j < nv; j += 64) {
            float e = fexp2((s_sc[qq][j] - mx) * LOG2E);
            s_sc[qq][j] = e;
            sum += e;
        }
#pragma unroll
        for (int off = 32; off > 0; off >>= 1) sum += __shfl_xor(sum, off);
        if (lane == 0) s_inv[qq] = frcp(sum);
    }
    __syncthreads();

    // ---- PV: thread -> (d-float4 = tid&63, k stride-8 chunk = tid>>6) ----
    {
        const int dl = tid & 63;
        const int kq = tid >> 6;
        float4 o0 = {0, 0, 0, 0}, o1 = {0, 0, 0, 0};
        const float4* v4 = (const float4*)(v + ((size_t)b * K_ << 8));
        for (int k = kq; k < nv; k += 8) {
            int vr = s_kidx[k];                       // wave-uniform -> coalesced v row
            float4 vv = v4[((size_t)vr << 6) + dl];
            float p0 = s_sc[0][k], p1 = s_sc[1][k];
            o0.x = fmaf(p0, vv.x, o0.x); o0.y = fmaf(p0, vv.y, o0.y);
            o0.z = fmaf(p0, vv.z, o0.z); o0.w = fmaf(p0, vv.w, o0.w);
            o1.x = fmaf(p1, vv.x, o1.x); o1.y = fmaf(p1, vv.y, o1.y);
            o1.z = fmaf(p1, vv.z, o1.z); o1.w = fmaf(p1, vv.w, o1.w);
        }
        s_pv[kq * 2 + 0][dl] = o0;
        s_pv[kq * 2 + 1][dl] = o1;
        __syncthreads();
        if (tid < 128) {
            const int qq = tid >> 6, c = tid & 63;
            float4 s = {0, 0, 0, 0};
#pragma unroll
            for (int g = 0; g < 8; ++g) {
                float4 x = s_pv[g * 2 + qq][c];
                s.x += x.x; s.y += x.y; s.z += x.z; s.w += x.w;
            }
            const float inv = s_inv[qq];
            s.x *= inv; s.y *= inv; s.z *= inv; s.w *= inv;
            ((float4*)out)[((size_t)(b * Q_ + q0 + qq) << 6) + c] = s;
        }
    }
}

extern "C" void kernel_launch(void* const* d_in, const int* in_sizes, int n_in,
                              void* d_out, int out_size, void* d_ws, size_t ws_size,
                              hipStream_t stream) {
    const float* q    = (const float*)d_in[0];
    const float* k    = (const float*)d_in[1];
    const float* v    = (const float*)d_in[2];
    const int*   mask = (const int*)d_in[3];
    const float* Wq   = (const float*)d_in[4];
    const float* Wk   = (const float*)d_in[5];
    const float* wv   = (const float*)d_in[6];
    float* out = (float*)d_out;

    float* qpE    = (float*)d_ws;                          // 1 MB  : exp2(c*qp) rows
    float* kpC    = qpE + (size_t)B_ * Q_ * D_;            // 4 MB  : exp2(c*kp) [b][e][slot]
    ushort* kidx  = (ushort*)(kpC + (size_t)B_ * 256 * NVPAD); // 8 KB
    short* slot_of = (short*)(kidx + (size_t)B_ * K_);     // 8 KB
    int* nvalid   = (int*)(slot_of + (size_t)B_ * K_);     // 16 B

    const float c2 = 2.885390082f;  // 2*log2(e)

    compact_kernel<<<dim3(B_), 64, 0, stream>>>(mask, kidx, slot_of, nvalid);
    proj_kernel<<<dim3(80, 4), 256, 0, stream>>>(q, k, Wq, Wk, slot_of, qpE, kpC, c2);
    attn_kernel<<<dim3(512), 512, 0, stream>>>(qpE, kpC, v, kidx, nvalid, wv, out);
}

// Round 11
// 62.070 us; speedup vs baseline: 1.2172x; 1.0851x over previous
//
#include <hip/hip_runtime.h>
#include <hip/hip_bf16.h>

#define B_ 4
#define Q_ 256
#define K_ 1024
#define D_ 256
#define NVPAD 1024
#define LOG2E 1.44269504f

__device__ __forceinline__ float fexp2(float x) {
    float r; asm("v_exp_f32 %0, %1" : "=v"(r) : "v"(x)); return r;
}
__device__ __forceinline__ float frcp(float x) {
    float r; asm("v_rcp_f32 %0, %1" : "=v"(r) : "v"(x)); return r;
}

// Grid = B, 64 threads. kidx[slot]=k, slot_of[k]=slot or -1, nvalid.
__global__ void compact_kernel(const int* __restrict__ mask,
                               ushort* __restrict__ kidx,
                               short* __restrict__ slot_of,
                               int* __restrict__ nvalid) {
    const int b = blockIdx.x, lane = threadIdx.x;
    const int* m = mask + b * K_;
    const int base = lane * 16;
    int cnt = 0;
#pragma unroll
    for (int i = 0; i < 16; ++i) cnt += (m[base + i] != 0);
    int inc = cnt;
#pragma unroll
    for (int d = 1; d < 64; d <<= 1) {
        int tt = __shfl_up(inc, d);
        if (lane >= d) inc += tt;
    }
    const int total = __shfl(inc, 63);
    int pos = inc - cnt;
    ushort* kb = kidx + b * K_;
    short* so  = slot_of + b * K_;
    for (int i = 0; i < 16; ++i) {
        int kk = base + i;
        if (m[kk] != 0) { kb[pos] = (ushort)kk; so[kk] = (short)pos; ++pos; }
        else so[kk] = -1;
    }
    for (int j = total + lane; j < K_; j += 64) kb[j] = 0;
    if (lane == 0) nvalid[b] = total;
}

// Grid (80,4), 256 thr. x<16: qpE[row][e] = exp2(c*q@Wq) row-major.
// x>=16: kpC[b][e4][slot]{4e} = exp2(c*k@Wk)  (tiled-transposed compacted).
__global__ __launch_bounds__(256) void proj_kernel(const float* __restrict__ q,
                                                   const float* __restrict__ k,
                                                   const float* __restrict__ Wq,
                                                   const float* __restrict__ Wk,
                                                   const short* __restrict__ slot_of,
                                                   float* __restrict__ qpE,
                                                   float* __restrict__ kpC,
                                                   float scale) {
    const int t = threadIdx.x;
    const bool isQ = blockIdx.x < 16;
    const float* A; const float* W; int m0;
    if (isQ) { A = q; W = Wq; m0 = blockIdx.x * 64; }
    else     { A = k; W = Wk; m0 = (blockIdx.x - 16) * 64; }

    __shared__ float As[16][65];
    __shared__ float Ws[16][64];
    __shared__ short s_slot[64];
    if (!isQ && t < 64) s_slot[t] = slot_of[m0 + t];

    const int tx = t & 15, ty = t >> 4;
    const int n0 = blockIdx.y * 64;
    const int ar = t >> 2, ac = (t & 3) * 4;
    const int wr = t >> 4, wc = (t & 15) * 4;
    float c[4][4] = {};
    for (int kb = 0; kb < 256; kb += 16) {
        __syncthreads();
        float4 av = *(const float4*)(A + (size_t)(m0 + ar) * 256 + kb + ac);
        As[ac + 0][ar] = av.x; As[ac + 1][ar] = av.y;
        As[ac + 2][ar] = av.z; As[ac + 3][ar] = av.w;
        float4 wvv = *(const float4*)(W + (size_t)(kb + wr) * 256 + n0 + wc);
        wvv.x *= scale; wvv.y *= scale; wvv.z *= scale; wvv.w *= scale;
        *(float4*)(&Ws[wr][wc]) = wvv;
        __syncthreads();
#pragma unroll
        for (int kk = 0; kk < 16; ++kk) {
            float4 bv = *(const float4*)(&Ws[kk][tx * 4]);
#pragma unroll
            for (int i = 0; i < 4; ++i) {
                float a = As[kk][ty * 4 + i];
                c[i][0] = fmaf(a, bv.x, c[i][0]);
                c[i][1] = fmaf(a, bv.y, c[i][1]);
                c[i][2] = fmaf(a, bv.z, c[i][2]);
                c[i][3] = fmaf(a, bv.w, c[i][3]);
            }
        }
    }
    if (isQ) {
#pragma unroll
        for (int i = 0; i < 4; ++i) {
            float4 o = make_float4(fexp2(c[i][0]), fexp2(c[i][1]),
                                   fexp2(c[i][2]), fexp2(c[i][3]));
            *(float4*)(qpE + (size_t)(m0 + ty * 4 + i) * 256 + n0 + tx * 4) = o;
        }
    } else {
        const int b = m0 >> 10;
        float* kpCb = kpC + (size_t)b * 256 * NVPAD;
        const int e4 = (n0 + tx * 4) >> 2;           // f4-group index along e
#pragma unroll
        for (int i = 0; i < 4; ++i) {
            const int sl = s_slot[ty * 4 + i];
            if (sl >= 0) {
                float4 o = make_float4(fexp2(c[i][0]), fexp2(c[i][1]),
                                       fexp2(c[i][2]), fexp2(c[i][3]));
                *(float4*)(kpCb + ((size_t)e4 * NVPAD + sl) * 4) = o;
            }
        }
    }
}

// Grid = 512 = B * 128 qpairs, 512 threads, ~26 KB LDS.
// LANE OWNS SLOT, tiled kpC: per eg one float4 load that is vectorized
// per-lane AND coalesced across lanes (consecutive slots). A0/A1/W are
// block-uniform global reads -> scalar-pipe s_load, zero VALU issue.
// No cross-lane reduction; 3 block barriers total.
__global__ __launch_bounds__(512, 2) void attn_kernel(const float* __restrict__ qpE,
                                                      const float* __restrict__ kpC,
                                                      const float* __restrict__ v,
                                                      const ushort* __restrict__ kidx_g,
                                                      const int* __restrict__ nvalid_g,
                                                      const float* __restrict__ wv,
                                                      float* __restrict__ out) {
    __shared__ ushort s_kidx[1024];       //  2 KB : compacted k indices (PV only)
    __shared__ float  s_sc[2][1024];      //  8 KB : scores then unnormalized probs
    __shared__ float4 s_pv[16][64];       // 16 KB : PV partials
    __shared__ float  s_inv[2];

    const int tid = threadIdx.x;

    int bid = blockIdx.x;
    bid = (bid & 7) * 64 + (bid >> 3);    // XCD swizzle: each XCD -> one batch's kpC
    const int b  = bid >> 7;
    const int qi = bid & 127;
    const int q0 = qi * 2;

    const int nv = nvalid_g[b];

    s_kidx[tid]       = (tid < nv)       ? kidx_g[b * K_ + tid]       : (ushort)0;
    s_kidx[tid + 512] = (tid + 512 < nv) ? kidx_g[b * K_ + tid + 512] : (ushort)0;

    // ---- scores: lane owns slot; per eg one f4 load (vector + coalesced) ----
    const float4* Bp  = (const float4*)(kpC + (size_t)b * 256 * NVPAD); // [64][NVPAD]
    const float4* A0p = (const float4*)(qpE + ((size_t)(b * Q_ + q0) << 8));
    const float4* A1p = A0p + 64;                     // next q row
    const float4* Wp  = (const float4*)wv;

    for (int s0 = tid; s0 < nv; s0 += 512) {
        float a0 = 0.f, a1 = 0.f;
#pragma unroll 8
        for (int eg = 0; eg < 64; ++eg) {
            float4 Bv = Bp[(size_t)eg * NVPAD + s0];  // per-lane f4, wave-coalesced
            float4 A0 = A0p[eg];                      // uniform -> s_load
            float4 A1 = A1p[eg];
            float4 W4 = Wp[eg];
            a0 = fmaf(W4.x, frcp(fmaf(A0.x, Bv.x, 1.f)), a0);
            a1 = fmaf(W4.x, frcp(fmaf(A1.x, Bv.x, 1.f)), a1);
            a0 = fmaf(W4.y, frcp(fmaf(A0.y, Bv.y, 1.f)), a0);
            a1 = fmaf(W4.y, frcp(fmaf(A1.y, Bv.y, 1.f)), a1);
            a0 = fmaf(W4.z, frcp(fmaf(A0.z, Bv.z, 1.f)), a0);
            a1 = fmaf(W4.z, frcp(fmaf(A1.z, Bv.z, 1.f)), a1);
            a0 = fmaf(W4.w, frcp(fmaf(A0.w, Bv.w, 1.f)), a0);
            a1 = fmaf(W4.w, frcp(fmaf(A1.w, Bv.w, 1.f)), a1);
        }
        s_sc[0][s0] = -2.f * a0;
        s_sc[1][s0] = -2.f * a1;
    }
    __syncthreads();

    // ---- softmax stats: wave qq < 2 handles q = qq ----
    const int lane = tid & 63;
    const int wave = tid >> 6;
    if (wave < 2) {
        const int qq = wave;
        float mx = -3.0e38f;
        for (int j = lane; j < nv; j += 64) mx = fmaxf(mx, s_sc[qq][j]);
#pragma unroll
        for (int off = 32; off > 0; off >>= 1) mx = fmaxf(mx, __shfl_xor(mx, off));
        float sum = 0.f;
        for (int j = lane; j < nv; j += 64) {
            float e = fexp2((s_sc[qq][j] - mx) * LOG2E);
            s_sc[qq][j] = e;
            sum += e;
        }
#pragma unroll
        for (int off = 32; off > 0; off >>= 1) sum += __shfl_xor(sum, off);
        if (lane == 0) s_inv[qq] = frcp(sum);
    }
    __syncthreads();

    // ---- PV: thread -> (d-float4 = tid&63, k stride-8 chunk = tid>>6) ----
    {
        const int dl = tid & 63;
        const int kq = tid >> 6;
        float4 o0 = {0, 0, 0, 0}, o1 = {0, 0, 0, 0};
        const float4* v4 = (const float4*)(v + ((size_t)b * K_ << 8));
        for (int k = kq; k < nv; k += 8) {
            int vr = s_kidx[k];                       // wave-uniform -> coalesced v row
            float4 vv = v4[((size_t)vr << 6) + dl];
            float p0 = s_sc[0][k], p1 = s_sc[1][k];
            o0.x = fmaf(p0, vv.x, o0.x); o0.y = fmaf(p0, vv.y, o0.y);
            o0.z = fmaf(p0, vv.z, o0.z); o0.w = fmaf(p0, vv.w, o0.w);
            o1.x = fmaf(p1, vv.x, o1.x); o1.y = fmaf(p1, vv.y, o1.y);
            o1.z = fmaf(p1, vv.z, o1.z); o1.w = fmaf(p1, vv.w, o1.w);
        }
        s_pv[kq * 2 + 0][dl] = o0;
        s_pv[kq * 2 + 1][dl] = o1;
        __syncthreads();
        if (tid < 128) {
            const int qq = tid >> 6, c = tid & 63;
            float4 s = {0, 0, 0, 0};
#pragma unroll
            for (int g = 0; g < 8; ++g) {
                float4 x = s_pv[g * 2 + qq][c];
                s.x += x.x; s.y += x.y; s.z += x.z; s.w += x.w;
            }
            const float inv = s_inv[qq];
            s.x *= inv; s.y *= inv; s.z *= inv; s.w *= inv;
            ((float4*)out)[((size_t)(b * Q_ + q0 + qq) << 6) + c] = s;
        }
    }
}

extern "C" void kernel_launch(void* const* d_in, const int* in_sizes, int n_in,
                              void* d_out, int out_size, void* d_ws, size_t ws_size,
                              hipStream_t stream) {
    const float* q    = (const float*)d_in[0];
    const float* k    = (const float*)d_in[1];
    const float* v    = (const float*)d_in[2];
    const int*   mask = (const int*)d_in[3];
    const float* Wq   = (const float*)d_in[4];
    const float* Wk   = (const float*)d_in[5];
    const float* wv   = (const float*)d_in[6];
    float* out = (float*)d_out;

    float* qpE    = (float*)d_ws;                          // 1 MB  : exp2(c*qp) rows
    float* kpC    = qpE + (size_t)B_ * Q_ * D_;            // 4 MB  : tiled-transposed
    ushort* kidx  = (ushort*)(kpC + (size_t)B_ * 256 * NVPAD); // 8 KB
    short* slot_of = (short*)(kidx + (size_t)B_ * K_);     // 8 KB
    int* nvalid   = (int*)(slot_of + (size_t)B_ * K_);     // 16 B

    const float c2 = 2.885390082f;  // 2*log2(e)

    compact_kernel<<<dim3(B_), 64, 0, stream>>>(mask, kidx, slot_of, nvalid);
    proj_kernel<<<dim3(80, 4), 256, 0, stream>>>(q, k, Wq, Wk, slot_of, qpE, kpC, c2);
    attn_kernel<<<dim3(512), 512, 0, stream>>>(qpE, kpC, v, kidx, nvalid, wv, out);
}